// Round 1
// baseline (866.605 us; speedup 1.0000x reference)
//
#include <hip/hip_runtime.h>
#include <math.h>

typedef unsigned long long u64;
typedef unsigned int u32;
typedef unsigned char u8;

#define Dd 64
#define Hd 128
#define Wdim 128
#define VOL 1048576              // 64*128*128
#define NTOT 2097152             // 2 batches
#define NWORDS 32768             // NTOT/64 bits words per bit-volume (covers both batches)
#define NW2 65536                // two bit-volumes (T and H) concatenated
#define RB 1024
#define RT 256

// ---------------- reduction helper (deterministic) ----------------
__device__ __forceinline__ void block_sum(double v, double* __restrict__ part, int slot, double* sd){
  sd[threadIdx.x] = v;
  __syncthreads();
  for(int s = RT>>1; s>0; s>>=1){
    if((int)threadIdx.x < s) sd[threadIdx.x] += sd[threadIdx.x + s];
    __syncthreads();
  }
  if(threadIdx.x==0) part[(size_t)slot*RB + blockIdx.x] = sd[0];
  __syncthreads();
}

// ---------------- init: prob, bitmasks, dice/ce/conn sums ----------------
// sums: 0=ce 1=tp1 2=sum_prob 3=sum_y 4=conn
__global__ __launch_bounds__(RT) void k_init(const float* __restrict__ net, const int* __restrict__ tgt,
    float* __restrict__ img, u64* __restrict__ ybits, u64* __restrict__ hbits,
    u64* __restrict__ bimg2, double* __restrict__ part)
{
  __shared__ double sd[RT];
  double ce=0, tp=0, spr=0, sy=0, conn=0;
  int g = blockIdx.x*RT + threadIdx.x;
  for(int n=g; n<NTOT; n += RB*RT){
    int b = n >> 20;
    int v = n & (VOL-1);
    const float* nb = net + (size_t)b*(2*VOL);
    float x0 = nb[v], x1 = nb[VOL+v];
    int t = tgt[n];
    int yb = (t>0) ? 1 : 0;
    float p = 1.f/(1.f+expf(x0-x1));       // softmax fg prob
    img[n] = p;
    u64 wy = __ballot(yb);
    u64 wh = __ballot(x1 > x0);            // prob > 0.5
    if((threadIdx.x & 63)==0){
      int wi = n>>6;
      ybits[wi]=wy; hbits[wi]=wh;
      bimg2[wi]=wy; bimg2[NWORDS+wi]=wh;
    }
    float mx = fmaxf(x0,x1);
    float lse = mx + logf(expf(x0-mx)+expf(x1-mx));
    ce += (double)(lse - (yb ? x1 : x0));
    tp += (double)p * yb;
    spr += (double)p;
    sy += (double)yb;
    conn += (double)((int)((x0>0.5f)!=(yb!=0)) + (int)((x1>0.5f)!=(yb!=0)));
  }
  block_sum(ce ,part,0,sd);
  block_sum(tp ,part,1,sd);
  block_sum(spr,part,2,sd);
  block_sum(sy ,part,3,sd);
  block_sum(conn,part,4,sd);
}

// ---------------- float morphology (OOB ignored per reduce_window -inf init) ----------------
__global__ __launch_bounds__(256) void f_erode7(const float* __restrict__ in, float* __restrict__ out){
  int n = blockIdx.x*256 + threadIdx.x;
  int x = n & 127, y = (n>>7)&127, z = (n>>14)&63;
  float m = in[n];
  if(x>0)   m = fminf(m, in[n-1]);
  if(x<127) m = fminf(m, in[n+1]);
  if(y>0)   m = fminf(m, in[n-128]);
  if(y<127) m = fminf(m, in[n+128]);
  if(z>0)   m = fminf(m, in[n-16384]);
  if(z<63)  m = fminf(m, in[n+16384]);
  out[n] = m;
}

__global__ __launch_bounds__(256) void f_dilate27(const float* __restrict__ in, float* __restrict__ out){
  int n = blockIdx.x*256 + threadIdx.x;
  int x = n & 127, y=(n>>7)&127, z=(n>>14)&63;
  int dz0 = (z>0)?-1:0, dz1=(z<63)?1:0;
  int dy0 = (y>0)?-1:0, dy1=(y<127)?1:0;
  float m = -1e30f;
  for(int dz=dz0; dz<=dz1; ++dz)
    for(int dy=dy0; dy<=dy1; ++dy){
      int base = n + dz*16384 + dy*128;
      float a = in[base];
      if(x>0)   a = fmaxf(a, in[base-1]);
      if(x<127) a = fmaxf(a, in[base+1]);
      m = fmaxf(m, a);
    }
  out[n] = m;
}

__global__ __launch_bounds__(256) void f_skel_init(float* __restrict__ skel, const float* __restrict__ img, const float* __restrict__ open_){
  int n = blockIdx.x*256 + threadIdx.x;
  skel[n] = fmaxf(img[n]-open_[n], 0.f);
}

__global__ __launch_bounds__(256) void f_skel_update(float* __restrict__ skel, const float* __restrict__ e1, const float* __restrict__ open_){
  int n = blockIdx.x*256 + threadIdx.x;
  float d = fmaxf(e1[n]-open_[n], 0.f);
  float s = skel[n];
  skel[n] = s + fmaxf(d - s*d, 0.f);
}

// ---------------- bit-packed binary morphology ----------------
// bit i of word = voxel x = xh*64+i; row = 2 words; OOB: erosion->1, dilation->0
__device__ __forceinline__ u64 erode_x_w(const u64* __restrict__ vol, int ri, int xh){
  u64 c = vol[ri];
  if(xh) return c & ((c<<1)|(vol[ri-1]>>63)) & ((c>>1)|(1ull<<63));
  else   return c & ((c<<1)|1ull)            & ((c>>1)|(vol[ri+1]<<63));
}
__device__ __forceinline__ u64 dilate_x_w(const u64* __restrict__ vol, int ri, int xh){
  u64 c = vol[ri];
  if(xh) return c | (c<<1) | (vol[ri-1]>>63) | (c>>1);
  else   return c | (c<<1) | (c>>1) | (vol[ri+1]<<63);
}

__global__ __launch_bounds__(256) void b_erode7(const u64* __restrict__ in, u64* __restrict__ out){
  int wi = blockIdx.x*256 + threadIdx.x;
  int li = wi & (NWORDS-1);
  const u64* vol = in + (wi - li);
  int xh = li & 1, y = (li>>1)&127, z = (li>>8)&63;
  u64 m = erode_x_w(vol, li, xh);
  if(y>0)   m &= vol[li-2];
  if(y<127) m &= vol[li+2];
  if(z>0)   m &= vol[li-256];
  if(z<63)  m &= vol[li+256];
  out[wi] = m;
}

__global__ __launch_bounds__(256) void b_dilate27(const u64* __restrict__ in, u64* __restrict__ out){
  int wi = blockIdx.x*256 + threadIdx.x;
  int li = wi & (NWORDS-1);
  const u64* vol = in + (wi - li);
  int xh = li & 1, y=(li>>1)&127, z=(li>>8)&63;
  u64 m = 0;
  for(int dz=-1; dz<=1; ++dz){
    int zz = z+dz; if(zz<0 || zz>=Dd) continue;
    for(int dy=-1; dy<=1; ++dy){
      int yy = y+dy; if(yy<0 || yy>=Hd) continue;
      m |= dilate_x_w(vol, li + dz*256 + dy*2, xh);
    }
  }
  out[wi] = m;
}

__global__ __launch_bounds__(256) void b_skel_init(u64* __restrict__ skel, const u64* __restrict__ img, const u64* __restrict__ open_){
  int wi = blockIdx.x*256 + threadIdx.x;
  skel[wi] = img[wi] & ~open_[wi];
}
__global__ __launch_bounds__(256) void b_skel_update(u64* __restrict__ skel, const u64* __restrict__ e1, const u64* __restrict__ open_){
  int wi = blockIdx.x*256 + threadIdx.x;
  skel[wi] |= e1[wi] & ~open_[wi];
}
__global__ __launch_bounds__(256) void b_copy2(u64* __restrict__ dst, const u64* __restrict__ y, const u64* __restrict__ h){
  int i = blockIdx.x*256 + threadIdx.x;
  dst[i] = y[i];
  dst[NWORDS+i] = h[i];
}

// EDT step: acc(bytes) += cur bits; next = 27-pt binary erode(cur). Handles both masks (NW2 words).
__global__ __launch_bounds__(256) void edt_step(const u64* __restrict__ cur, u64* __restrict__ next, u32* __restrict__ acc4){
  int wi = blockIdx.x*256 + threadIdx.x;
  int li = wi & (NWORDS-1);
  const u64* vol = cur + (wi - li);
  int xh = li & 1, y=(li>>1)&127, z=(li>>8)&63;
  u64 c = vol[li];
  u32* a = acc4 + (size_t)wi*16;
  #pragma unroll
  for(int k=0;k<16;k++){
    u32 nib = (u32)((c >> (4*k)) & 0xFull);
    a[k] += (nib&1u) | ((nib&2u)<<7) | ((nib&4u)<<14) | ((nib&8u)<<21);
  }
  u64 m = ~0ull;
  for(int dz=-1; dz<=1; ++dz){
    int zz=z+dz; if(zz<0||zz>=Dd) continue;
    for(int dy=-1; dy<=1; ++dy){
      int yy=y+dy; if(yy<0||yy>=Hd) continue;
      m &= erode_x_w(vol, li + dz*256 + dy*2, xh);
    }
  }
  next[wi] = m;
}

// mm: [0..1]=rmaxT(b) [2..3]=rminT(b) [4..5]=rmaxH(b) [6..7]=rminH(b)
__global__ void init_mm(u32* mm){
  int i = threadIdx.x;
  if(i<8) mm[i] = (i==2||i==3||i==6||i==7) ? 0xFFFFFFFFu : 0u;
}

__global__ __launch_bounds__(256) void rminmax(const u64* __restrict__ skel2, const u64* __restrict__ hbits,
                                               const u8* __restrict__ acc, u32* __restrict__ mm){
  int wi = blockIdx.x*256 + threadIdx.x;
  int sel = wi >> 15;
  int li = wi & (NWORDS-1);
  int b = (li>>14)&1;
  u64 s = sel ? (skel2[NWORDS+li] & hbits[li]) : skel2[li];
  const u8* av = acc + (size_t)sel*NTOT + ((size_t)li<<6);
  u32 mx=0, mn=0xFFFFFFFFu;
  for(int i=0;i<64;i++){
    u32 r = ((s>>i)&1ull) ? (u32)av[i] : 0u;
    mx = mx>r?mx:r;
    mn = mn<r?mn:r;
  }
  for(int off=32; off>0; off>>=1){
    u32 omx = (u32)__shfl_down((int)mx, off);
    u32 omn = (u32)__shfl_down((int)mn, off);
    mx = mx>omx?mx:omx;
    mn = mn<omn?mn:omn;
  }
  if((threadIdx.x&63)==0){
    atomicMax(&mm[sel*4+b], mx);
    atomicMin(&mm[sel*4+2+b], mn);
  }
}

// ---------------- directional (Sobel) loss: slot 5 ----------------
__global__ __launch_bounds__(RT) void k_sobel(const float* __restrict__ net, const int* __restrict__ tgt, double* __restrict__ part){
  __shared__ double sd[RT];
  double accd = 0;
  int g = blockIdx.x*RT + threadIdx.x;
  for(int n=g; n<NTOT; n+=RB*RT){
    int b = n>>20;
    int x = n&127, y=(n>>7)&127, z=(n>>14)&63;
    const float* P = net + (size_t)b*(2*VOL);     // channel 0 only (channel-1 kernel is zeros)
    const int*   T = tgt + (size_t)b*VOL;
    float gpx=0,gpy=0,gpz=0,gtx=0,gty=0,gtz=0;
    const float SM[3] = {1.f,2.f,1.f};
    const float DV[3] = {-1.f,0.f,1.f};
    #pragma unroll
    for(int da=0;da<3;da++){
      int zz=z+da-1; bool zok = ((unsigned)zz < 64u);
      #pragma unroll
      for(int db=0;db<3;db++){
        int yy=y+db-1; bool yok = ((unsigned)yy < 128u);
        #pragma unroll
        for(int dc=0;dc<3;dc++){
          int xx=x+dc-1;
          float pv=0.f, tv=0.f;
          if(zok && yok && (unsigned)xx<128u){
            int idx = (zz<<14)+(yy<<7)+xx;
            pv = P[idx]; tv = (float)T[idx];
          }
          float wx = SM[db]*DV[dc];       // kx[d,h,w]=sx[h][w]
          float wy = SM[da]*DV[dc];       // ky[d,h,w]=sx[d][w]
          float wz = DV[da]*SM[dc];       // kz[d,h,w]=sx[w][d]
          gpx += pv*wx; gpy += pv*wy; gpz += pv*wz;
          gtx += tv*wx; gty += tv*wy; gtz += tv*wz;
        }
      }
    }
    float np_ = sqrtf(gpx*gpx+gpy*gpy+gpz*gpz);
    float nt_ = sqrtf(gtx*gtx+gty*gty+gtz*gtz);
    float ip = 1.f/fmaxf(np_,1e-12f);
    float it = 1.f/fmaxf(nt_,1e-12f);
    float num = (gpx*gtx+gpy*gty+gpz*gtz)*ip*it;
    float den = fmaxf((np_*ip)*(nt_*it), 1e-8f);
    accd += (double)(num/den);
  }
  block_sum(accd, part, 5, sd);
}

// ---------------- final per-voxel reduce: cldice + union sums (slots 6..13) ----------------
__global__ __launch_bounds__(RT) void k_final(const float* __restrict__ net, const float* __restrict__ skelp,
    const u64* __restrict__ ybits, const u64* __restrict__ hbits, const u64* __restrict__ skel2,
    const u8* __restrict__ acc, const u32* __restrict__ mm, double* __restrict__ part)
{
  __shared__ double sd[RT];
  double cl1=0,cl2=0,cl3=0,cl4=0,i1=0,un1=0,i2=0,un2=0;
  float rmaxT_[2], rminT_[2], rmaxH_[2], rminH_[2];
  for(int b=0;b<2;b++){
    rmaxT_[b] = fmaxf((float)mm[b],1.f);
    rminT_[b] = fmaxf((float)mm[2+b],1.f);
    rmaxH_[b] = fmaxf((float)mm[4+b],1.f);
    rminH_[b] = fmaxf((float)mm[6+b],1.f);
  }
  int g = blockIdx.x*RT + threadIdx.x;
  for(int n=g; n<NTOT; n+=RB*RT){
    int b = n>>20, v = n&(VOL-1);
    int wi = n>>6, bit = n&63;
    int y  = (int)((ybits[wi]>>bit)&1ull);
    int hd = (int)((hbits[wi]>>bit)&1ull);
    int sT = (int)((skel2[wi]>>bit)&1ull);
    int sH = (int)((skel2[NWORDS+wi]>>bit)&1ull);
    float dT = (float)acc[n];
    float dH = (float)acc[NTOT+n];
    const float* nb = net + (size_t)b*(2*VOL);
    float x0=nb[v], x1=nb[VOL+v];
    float p = 1.f/(1.f+expf(x0-x1));
    float sk = skelp[n];
    cl1 += (double)sk * y;
    cl2 += (double)sk;
    cl3 += sT ? (double)p : 0.0;
    cl4 += (double)sT;
    float q_vl = y ? fminf(dT, rmaxT_[b])/rmaxT_[b] : 0.f;
    float q_sl = 0.f;
    if(sT){ float t = (rmaxT_[b]-dT+rminT_[b])/rmaxT_[b]; q_sl = t*t; }
    float q_vp = fminf(dH, rmaxH_[b])/rmaxH_[b] * p;
    float q_sp = 0.f;
    if(sH & hd){ float t = (rmaxH_[b]-dH+rminH_[b])/rmaxH_[b]; q_sp = t*t*p; }
    i1  += (double)( q_sp * powf(q_sp+1e-4f, 0.7f) * q_vl );
    un1 += (double)( q_sp * (0.1f*q_sp + 0.9f*q_vl) );
    i2  += (double)( q_sl * powf(q_vp+1e-4f, 0.7f) * q_sl );
    un2 += (double)( q_sl * (0.1f*q_vp + 0.9f*q_sl) );
  }
  block_sum(cl1,part,6,sd);  block_sum(cl2,part,7,sd);
  block_sum(cl3,part,8,sd);  block_sum(cl4,part,9,sd);
  block_sum(i1 ,part,10,sd); block_sum(un1,part,11,sd);
  block_sum(i2 ,part,12,sd); block_sum(un2,part,13,sd);
}

// ---------------- finalize scalar ----------------
__global__ __launch_bounds__(RT) void k_finalize(const double* __restrict__ part, float* __restrict__ out){
  __shared__ double sd[RT];
  __shared__ double tot[14];
  for(int s=0;s<14;s++){
    double v=0;
    for(int i=threadIdx.x;i<RB;i+=RT) v += part[(size_t)s*RB+i];
    sd[threadIdx.x]=v; __syncthreads();
    for(int k=RT>>1;k>0;k>>=1){ if((int)threadIdx.x<k) sd[threadIdx.x]+=sd[threadIdx.x+k]; __syncthreads(); }
    if(threadIdx.x==0) tot[s]=sd[0];
    __syncthreads();
  }
  if(threadIdx.x==0){
    const double N = (double)NTOT;
    double ce = tot[0]/N;
    double tp=tot[1], fp=tot[2]-tot[1], fn=tot[3]-tot[1];
    double dice = -((2.0*tp+1e-5)/(2.0*tp+fp+fn+1e-5));
    double conn = tot[4]/(2.0*N);
    double dir  = 1.0 - tot[5]/N;
    double tprec = (tot[6]+1.0)/(tot[7]+1.0);
    double tsens = (tot[8]+1.0)/(tot[9]+1.0);
    double cld = 1.0 - 2.0*tprec*tsens/(tprec+tsens);
    double u1 = 1.0 - (tot[10]+1.0)/(tot[11]+1.0);
    double u2 = 1.0 - (tot[12]+1.0)/(tot[13]+1.0);
    out[0] = (float)(dice+ce+cld+dir+conn+u1+u2);
  }
}

extern "C" void kernel_launch(void* const* d_in, const int* in_sizes, int n_in,
                              void* d_out, int out_size, void* d_ws, size_t ws_size,
                              hipStream_t stream)
{
  (void)in_sizes; (void)n_in; (void)out_size; (void)ws_size;
  const float* net = (const float*)d_in[0];
  const int*   tgt = (const int*)d_in[1];
  float* out = (float*)d_out;
  char* w = (char*)d_ws;
  const size_t MB = 1024*1024;
  // workspace layout (~40.2 MB total)
  float* F1 = (float*)(w + 0*MB);    // img / scratch
  float* F2 = (float*)(w + 8*MB);    // skel_pred (soft)
  float* F3 = (float*)(w + 16*MB);   // t1
  float* F4 = (float*)(w + 24*MB);   // t2
  u64* ybits = (u64*)(w + 32*MB);
  u64* hbits = ybits + NWORDS;
  u64* skel2 = hbits + NWORDS;       // [0]=skelT [1]=skelH
  u64* bimg  = skel2 + 2*NWORDS;
  u64* bt1   = bimg + 2*NWORDS;
  u64* bt2   = bt1 + 2*NWORDS;
  u64* bt3   = bt2 + 2*NWORDS;
  u64* cur   = bt3 + 2*NWORDS;
  u64* nxt   = cur + 2*NWORDS;
  u8*  acc   = (u8*)(nxt + 2*NWORDS);         // [2][NTOT] EDT byte counters (4 MB)
  double* part = (double*)(acc + (size_t)2*NTOT);
  u32* mm = (u32*)(part + (size_t)14*RB);

  hipMemsetAsync(acc, 0, (size_t)2*NTOT, stream);
  init_mm<<<1, 64, 0, stream>>>(mm);
  k_init<<<RB, RT, 0, stream>>>(net, tgt, F1, ybits, hbits, bimg, part);

  const int GF = NTOT/256;
  // ---- float soft_skel(prob, 10) ----
  f_erode7<<<GF,256,0,stream>>>(F1, F3);
  f_dilate27<<<GF,256,0,stream>>>(F3, F4);
  f_skel_init<<<GF,256,0,stream>>>(F2, F1, F4);
  {
    float* img=F1; float* t1=F3; float* t2=F4;
    for(int it=0; it<10; ++it){
      f_erode7<<<GF,256,0,stream>>>(img, t1);      // e1 = new img
      f_erode7<<<GF,256,0,stream>>>(t1, t2);       // e2
      f_dilate27<<<GF,256,0,stream>>>(t2, img);    // open -> old img buf
      f_skel_update<<<GF,256,0,stream>>>(F2, t1, img);
      float* tmp=img; img=t1; t1=tmp;
    }
  }
  // ---- binary soft_skel for y_true and hard (bit-packed, both in one grid) ----
  const int GB = NW2/256;
  {
    u64 *bi=bimg, *b1=bt1, *b2=bt2, *b3=bt3;
    b_erode7<<<GB,256,0,stream>>>(bi, b1);
    b_dilate27<<<GB,256,0,stream>>>(b1, b2);
    b_skel_init<<<GB,256,0,stream>>>(skel2, bi, b2);
    for(int it=0; it<10; ++it){
      b_erode7<<<GB,256,0,stream>>>(bi, b1);
      b_erode7<<<GB,256,0,stream>>>(b1, b2);
      b_dilate27<<<GB,256,0,stream>>>(b2, b3);
      b_skel_update<<<GB,256,0,stream>>>(skel2, b1, b3);
      u64* tmp=bi; bi=b1; b1=tmp;
    }
  }
  // ---- EDT (16 iters) for both masks ----
  b_copy2<<<NWORDS/256,256,0,stream>>>(cur, ybits, hbits);
  {
    u64 *c=cur, *x=nxt;
    for(int it=0; it<16; ++it){
      edt_step<<<GB,256,0,stream>>>(c, x, (u32*)acc);
      u64* tmp=c; c=x; x=tmp;
    }
  }
  rminmax<<<GB,256,0,stream>>>(skel2, hbits, acc, mm);
  k_sobel<<<RB,RT,0,stream>>>(net, tgt, part);
  k_final<<<RB,RT,0,stream>>>(net, F2, ybits, hbits, skel2, acc, mm, part);
  k_finalize<<<1,RT,0,stream>>>(part, out);
}

// Round 2
// 815.446 us; speedup vs baseline: 1.0627x; 1.0627x over previous
//
#include <hip/hip_runtime.h>
#include <math.h>

typedef unsigned long long u64;
typedef unsigned int u32;
typedef unsigned char u8;

#define VOL 1048576              // 64*128*128
#define NTOT 2097152             // 2 batches
#define NWORDS 32768             // NTOT/64
#define RB 1024
#define RT 256
#define PINF 1e30f
#define NINF -1e30f

// ---------------- reduction helper (deterministic) ----------------
__device__ __forceinline__ void block_sum(double v, double* __restrict__ part, int slot, double* sd){
  sd[threadIdx.x] = v;
  __syncthreads();
  for(int s = RT>>1; s>0; s>>=1){
    if((int)threadIdx.x < s) sd[threadIdx.x] += sd[threadIdx.x + s];
    __syncthreads();
  }
  if(threadIdx.x==0) part[(size_t)slot*RB + blockIdx.x] = sd[0];
  __syncthreads();
}

// ---------------- init: prob, bitmasks, dice/ce/conn sums ----------------
__global__ __launch_bounds__(RT) void k_init(const float* __restrict__ net, const int* __restrict__ tgt,
    float* __restrict__ img, u64* __restrict__ ybits, u64* __restrict__ hbits,
    u64* __restrict__ bimg2, double* __restrict__ part)
{
  __shared__ double sd[RT];
  double ce=0, tp=0, spr=0, sy=0, conn=0;
  int g = blockIdx.x*RT + threadIdx.x;
  for(int n=g; n<NTOT; n += RB*RT){
    int b = n >> 20;
    int v = n & (VOL-1);
    const float* nb = net + (size_t)b*(2*VOL);
    float x0 = nb[v], x1 = nb[VOL+v];
    int t = tgt[n];
    int yb = (t>0) ? 1 : 0;
    float p = 1.f/(1.f+expf(x0-x1));
    img[n] = p;
    u64 wy = __ballot(yb);
    u64 wh = __ballot(x1 > x0);
    if((threadIdx.x & 63)==0){
      int wi = n>>6;
      ybits[wi]=wy; hbits[wi]=wh;
      bimg2[wi]=wy; bimg2[NWORDS+wi]=wh;
    }
    float mx = fmaxf(x0,x1);
    float lse = mx + logf(expf(x0-mx)+expf(x1-mx));
    ce += (double)(lse - (yb ? x1 : x0));
    tp += (double)p * yb;
    spr += (double)p;
    sy += (double)yb;
    conn += (double)((int)((x0>0.5f)!=(yb!=0)) + (int)((x1>0.5f)!=(yb!=0)));
  }
  block_sum(ce ,part,0,sd);
  block_sum(tp ,part,1,sd);
  block_sum(spr,part,2,sd);
  block_sum(sy ,part,3,sd);
  block_sum(conn,part,4,sd);
}

// ---------------- fused float soft-skel iteration (z-march, LDS rings) ----------------
// Per dispatch, from img: e1 = erode(img) (or img copy if INIT), e2 = erode(e1),
// open = dilate27(e2), d = relu(e1-open), skel update; writes e1 as new img (loop mode).
#define TX 64
#define TY 8
#define ZC 8
#define IW (TX+6)
#define IH (TY+6)
#define EW (TX+4)
#define EH (TY+4)
#define E2W (TX+2)
#define E2H (TY+2)

template<bool INIT>
__global__ __launch_bounds__(256) void fskel(const float* __restrict__ imgin, float* __restrict__ imgout,
                                             float* __restrict__ skel)
{
  __shared__ float simg[3][IH][IW];
  __shared__ float se1[3][EH][EW];
  __shared__ float se2[E2H][E2W];
  __shared__ float sM[3][TY][TX];
  int bid = blockIdx.x;
  int txb = bid & 1, tyb = (bid>>1)&15, tzb = (bid>>5)&7, b = bid>>8;
  int X0 = txb*TX, Y0 = tyb*TY, z0 = tzb*ZC, z1 = z0+ZC;
  const float* vol = imgin + (size_t)b*VOL;
  float* volo = imgout + (size_t)b*VOL;
  float* skl = skel + (size_t)b*VOL;
  int tid = threadIdx.x;

  for (int s = z0-3; s <= z1+2; ++s){
    { // load img slice s (OOB -> +INF, erode-neutral)
      float* dst = &simg[(s+6)%3][0][0];
      bool zok = (s>=0 && s<64);
      for (int idx=tid; idx<IH*IW; idx+=256){
        int ly = idx/IW, lx = idx-ly*IW;
        int gy = Y0-3+ly, gx = X0-3+lx;
        float v = PINF;
        if (zok && (unsigned)gy<128u && (unsigned)gx<128u)
          v = vol[(s<<14)+(gy<<7)+gx];
        dst[idx] = v;
      }
    }
    __syncthreads();
    int t = s-1;
    if (t >= z0-2){ // e1(t)
      float* dst = &se1[(t+6)%3][0][0];
      const float (*i0)[IW] = simg[(t+5)%3];
      const float (*i1)[IW] = simg[(t+6)%3];
      const float (*i2)[IW] = simg[(t+7)%3];
      bool zok = (t>=0 && t<64);
      for (int idx=tid; idx<EH*EW; idx+=256){
        int ly = idx/EW, lx = idx-ly*EW;
        int gy = Y0-2+ly, gx = X0-2+lx;
        float v = PINF;
        if (zok && (unsigned)gy<128u && (unsigned)gx<128u){
          if (INIT) v = i1[ly+1][lx+1];
          else {
            v = fminf(fminf(i1[ly+1][lx], i1[ly+1][lx+1]), i1[ly+1][lx+2]);
            v = fminf(v, fminf(i1[ly][lx+1], i1[ly+2][lx+1]));
            v = fminf(v, fminf(i0[ly+1][lx+1], i2[ly+1][lx+1]));
          }
        }
        dst[idx] = v;
      }
    }
    __syncthreads();
    int u = s-2;
    if (u >= z0-1){ // e2(u) then Mxy(u)
      const float (*e0)[EW] = se1[(u+5)%3];
      const float (*e1c)[EW] = se1[(u+6)%3];
      const float (*e2s)[EW] = se1[(u+7)%3];
      bool zok = (u>=0 && u<64);
      float* fse2 = &se2[0][0];
      for (int idx=tid; idx<E2H*E2W; idx+=256){
        int ly = idx/E2W, lx = idx-ly*E2W;
        int gy = Y0-1+ly, gx = X0-1+lx;
        float v = NINF; // dilate-neutral at OOB positions
        if (zok && (unsigned)gy<128u && (unsigned)gx<128u){
          v = fminf(fminf(e1c[ly+1][lx], e1c[ly+1][lx+1]), e1c[ly+1][lx+2]);
          v = fminf(v, fminf(e1c[ly][lx+1], e1c[ly+2][lx+1]));
          v = fminf(v, fminf(e0[ly+1][lx+1], e2s[ly+1][lx+1]));
        }
        fse2[idx] = v;
      }
      __syncthreads();
      float* dm = &sM[(u+6)%3][0][0];
      for (int idx=tid; idx<TY*TX; idx+=256){
        int ly = idx/TX, lx = idx-ly*TX;
        float v =            fmaxf(fmaxf(se2[ly  ][lx], se2[ly  ][lx+1]), se2[ly  ][lx+2]);
        v = fmaxf(v, fmaxf(fmaxf(se2[ly+1][lx], se2[ly+1][lx+1]), se2[ly+1][lx+2]));
        v = fmaxf(v, fmaxf(fmaxf(se2[ly+2][lx], se2[ly+2][lx+1]), se2[ly+2][lx+2]));
        dm[idx] = v;
      }
    }
    __syncthreads();
    int z = s-3;
    if (z >= z0){ // output
      const float (*m0)[TX] = sM[(z+5)%3];
      const float (*m1)[TX] = sM[(z+6)%3];
      const float (*m2)[TX] = sM[(z+7)%3];
      const float (*e1r)[EW] = se1[(z+6)%3];
      for (int idx=tid; idx<TY*TX; idx+=256){
        int ly = idx/TX, lx = idx-ly*TX;
        float open_ = fmaxf(fmaxf(m0[ly][lx], m1[ly][lx]), m2[ly][lx]);
        float e1v = e1r[ly+2][lx+2];
        float d = fmaxf(e1v - open_, 0.f);
        int n = (z<<14) + ((Y0+ly)<<7) + (X0+lx);
        if (INIT) skl[n] = d;
        else {
          float so = skl[n];
          skl[n] = so + fmaxf(d - so*d, 0.f);
          volo[n] = e1v;
        }
      }
    }
    __syncthreads();
  }
}

// ---------------- fused binary soft-skel iteration (bit-planes, LDS rings) ----------------
#define ZCB 8
__device__ __forceinline__ u64 berode_x(const u64* P, int tid){
  u64 c = P[tid];
  if (tid & 1) return c & ((c<<1)|(P[tid-1]>>63)) & ((c>>1)|(1ull<<63));
  else         return c & ((c<<1)|1ull) & ((c>>1)|(P[tid+1]<<63));
}
__device__ __forceinline__ u64 bdilate_x(const u64* P, int tid){
  u64 c = P[tid];
  if (tid & 1) return c | (c<<1) | (P[tid-1]>>63) | (c>>1);
  else         return c | (c<<1) | (c>>1) | (P[tid+1]<<63);
}

template<bool INIT>
__global__ __launch_bounds__(256) void bskel(const u64* __restrict__ imgin, u64* __restrict__ imgout,
                                             u64* __restrict__ skel)
{
  __shared__ u64 simg[3][256];
  __shared__ u64 se1[3][256];
  __shared__ u64 se2[256];
  __shared__ u64 sM[3][256];
  int bid = blockIdx.x;
  int tzb = bid & 7, b = (bid>>3)&1, m = bid>>4;
  int z0 = tzb*ZCB, z1 = z0+ZCB;
  size_t base = (size_t)m*NWORDS + (size_t)b*16384;
  const u64* vin = imgin + base;
  u64* vout = imgout + base;
  u64* skl = skel + base;
  int tid = threadIdx.x;
  int y = tid>>1;

  for (int s = z0-3; s <= z1+2; ++s){
    simg[(s+6)%3][tid] = (s>=0 && s<64) ? vin[(s<<8)+tid] : ~0ull;
    __syncthreads();
    int t = s-1;
    if (t >= z0-2){
      u64 r = ~0ull;
      if (t>=0 && t<64){
        const u64* P = simg[(t+6)%3];
        if (INIT) r = P[tid];
        else {
          r = berode_x(P, tid);
          if (y>0)   r &= P[tid-2];
          if (y<127) r &= P[tid+2];
          r &= simg[(t+5)%3][tid];
          r &= simg[(t+7)%3][tid];
        }
      }
      se1[(t+6)%3][tid] = r;
    }
    __syncthreads();
    int u = s-2;
    if (u >= z0-1){
      u64 r = 0;
      if (u>=0 && u<64){
        const u64* P = se1[(u+6)%3];
        r = berode_x(P, tid);
        if (y>0)   r &= P[tid-2];
        if (y<127) r &= P[tid+2];
        r &= se1[(u+5)%3][tid];
        r &= se1[(u+7)%3][tid];
      }
      se2[tid] = r;
      __syncthreads();
      u64 dm = bdilate_x(se2, tid);
      if (y>0)   dm |= bdilate_x(se2, tid-2);
      if (y<127) dm |= bdilate_x(se2, tid+2);
      sM[(u+6)%3][tid] = dm;
    }
    __syncthreads();
    int z = s-3;
    if (z >= z0){
      u64 open_ = sM[(z+5)%3][tid] | sM[(z+6)%3][tid] | sM[(z+7)%3][tid];
      u64 e1v = se1[(z+6)%3][tid];
      u64 d = e1v & ~open_;
      int gw = (z<<8)+tid;
      if (INIT) skl[gw] = d;
      else { skl[gw] |= d; vout[gw] = e1v; }
    }
    __syncthreads();
  }
}

// ---------------- separable Chebyshev EDT: acc = min(16, dist-to-bg) ----------------
// pass X: per-voxel O(1) via 64-bit window + clz/ffs
__global__ __launch_bounds__(256) void edt_px(const u64* __restrict__ yb, const u64* __restrict__ hb,
                                              u8* __restrict__ d)
{
  int g = blockIdx.x*256 + threadIdx.x;   // [0, 2*NTOT)
  int m = g >> 21;
  int n = g & (NTOT-1);
  const u64* bits = m ? hb : yb;
  int x = n & 127;
  int row = n >> 7;
  u64 w0 = bits[row*2], w1 = bits[row*2+1];
  int a = x - 31;
  u64 win;
  if (a < 0)        win = w0 << (-a);
  else if (a == 0)  win = w0;
  else if (a < 64)  win = (w0 >> a) | (w1 << (64-a));
  else              win = w1 >> (a-64);
  if (x < 31)  win |= (1ull << (31-x)) - 1;     // OOB low = fg
  if (x > 95)  win |= (~0ull) << (159-x);      // OOB high = fg
  u64 inv = ~win;
  u64 tl = inv & 0xFFFFFFFFull;   // bits 0..31 = voxels x-31..x
  u64 tr = inv >> 31;             // bit k = voxel x+k
  int dl = tl ? (31 - (63 - __clzll(tl))) : 99;
  int dr = tr ? (__ffsll((unsigned long long)tr) - 1) : 99;
  int dd = min(min(dl, dr), 16);
  d[(size_t)m*NTOT + n] = (u8)dd;
}

// passes Y/Z: d'(v) = min_k max(|k|, d(v+k*STRIDE)), early-exit
template<int STRIDE, int LIM, int SHIFT>
__global__ __launch_bounds__(256) void edt_pyz(const u8* __restrict__ din, u8* __restrict__ dout){
  int g = blockIdx.x*256 + threadIdx.x;
  int m = g >> 21;
  int n = g & (NTOT-1);
  int c = (n >> SHIFT) & (LIM-1);
  size_t idx = (size_t)m*NTOT + n;
  int best = din[idx];
  #pragma unroll 4
  for (int k=1; k<=16; ++k){
    if (best <= k) break;
    int v = 255;
    if (c-k >= 0)  v = din[idx - (size_t)k*STRIDE];
    if (c+k < LIM) v = min(v, (int)din[idx + (size_t)k*STRIDE]);
    best = min(best, max(k, v));
  }
  dout[idx] = (u8)best;
}

// mm: [0..1]=rmaxT(b) [2..3]=rminT(b) [4..5]=rmaxH(b) [6..7]=rminH(b)
__global__ void init_mm(u32* mm){
  int i = threadIdx.x;
  if(i<8) mm[i] = (i==2||i==3||i==6||i==7) ? 0xFFFFFFFFu : 0u;
}

__global__ __launch_bounds__(256) void rminmax(const u64* __restrict__ skel2, const u64* __restrict__ hbits,
                                               const u8* __restrict__ acc, u32* __restrict__ mm){
  int wi = blockIdx.x*256 + threadIdx.x;
  int sel = wi >> 15;
  int li = wi & (NWORDS-1);
  int b = (li>>14)&1;
  u64 s = sel ? (skel2[NWORDS+li] & hbits[li]) : skel2[li];
  const u8* av = acc + (size_t)sel*NTOT + ((size_t)li<<6);
  u32 mx=0, mn=0xFFFFFFFFu;
  for(int i=0;i<64;i++){
    u32 r = ((s>>i)&1ull) ? (u32)av[i] : 0u;
    mx = mx>r?mx:r;
    mn = mn<r?mn:r;
  }
  for(int off=32; off>0; off>>=1){
    u32 omx = (u32)__shfl_down((int)mx, off);
    u32 omn = (u32)__shfl_down((int)mn, off);
    mx = mx>omx?mx:omx;
    mn = mn<omn?mn:omn;
  }
  if((threadIdx.x&63)==0){
    atomicMax(&mm[sel*4+b], mx);
    atomicMin(&mm[sel*4+2+b], mn);
  }
}

// ---------------- fused sobel + final reduce: slots 5..13 ----------------
__global__ __launch_bounds__(RT) void k_tail(const float* __restrict__ net, const float* __restrict__ skelp,
    const u64* __restrict__ ybits, const u64* __restrict__ hbits, const u64* __restrict__ skel2,
    const u8* __restrict__ acc, const u32* __restrict__ mm, double* __restrict__ part)
{
  __shared__ double sd[RT];
  double sob=0, cl1=0,cl2=0,cl3=0,cl4=0,i1=0,un1=0,i2=0,un2=0;
  float rmaxT_[2], rminT_[2], rmaxH_[2], rminH_[2];
  for(int b=0;b<2;b++){
    rmaxT_[b]=fmaxf((float)mm[b],1.f);   rminT_[b]=fmaxf((float)mm[2+b],1.f);
    rmaxH_[b]=fmaxf((float)mm[4+b],1.f); rminH_[b]=fmaxf((float)mm[6+b],1.f);
  }
  const int SMi[3]={1,2,1}, DVi[3]={-1,0,1};
  int g = blockIdx.x*RT + threadIdx.x;
  for(int n=g; n<NTOT; n+=RB*RT){
    int b=n>>20, v=n&(VOL-1);
    int x=n&127, y=(n>>7)&127, z=(n>>14)&63;
    const float* P = net + (size_t)b*(2*VOL);
    // ---- sobel (separable along x; T gradients integer from ybits) ----
    float gpx=0,gpy=0,gpz=0;
    int gtx=0,gty=0,gtz=0;
    #pragma unroll
    for(int da=0;da<3;da++){
      int zz=z+da-1; if((unsigned)zz>=64u) continue;
      #pragma unroll
      for(int db=0;db<3;db++){
        int yy=y+db-1; if((unsigned)yy>=128u) continue;
        int rowv = (zz<<14)+(yy<<7)+x;
        float p0 = (x>0)?   P[rowv-1] : 0.f;
        float p1 = P[rowv];
        float p2 = (x<127)? P[rowv+1] : 0.f;
        float ep = p2-p0, sp = p0+2.f*p1+p2;
        gpx += (float)SMi[db]*ep;
        gpy += (float)SMi[da]*ep;
        gpz += (float)DVi[da]*sp;
        int nv = (b<<20)+rowv;
        int wi = nv>>6, bit = nv&63;
        u64 w = ybits[wi];
        int b1 = (int)((w>>bit)&1ull);
        int bm = 0, bp = 0;
        if (x>0)   bm = (bit==0)  ? (int)((ybits[wi-1]>>63)&1ull) : (int)((w>>(bit-1))&1ull);
        if (x<127) bp = (bit==63) ? (int)( ybits[wi+1]      &1ull) : (int)((w>>(bit+1))&1ull);
        int et = bp-bm, st = bm+2*b1+bp;
        gtx += SMi[db]*et;
        gty += SMi[da]*et;
        gtz += DVi[da]*st;
      }
    }
    float fgtx=(float)gtx, fgty=(float)gty, fgtz=(float)gtz;
    float np_=sqrtf(gpx*gpx+gpy*gpy+gpz*gpz);
    float nt_=sqrtf(fgtx*fgtx+fgty*fgty+fgtz*fgtz);
    float ip=1.f/fmaxf(np_,1e-12f), it=1.f/fmaxf(nt_,1e-12f);
    float num=(gpx*fgtx+gpy*fgty+gpz*fgtz)*ip*it;
    float den=fmaxf((np_*ip)*(nt_*it),1e-8f);
    sob += (double)(num/den);
    // ---- final sums ----
    int wi0 = n>>6, bit0 = n&63;
    int yb = (int)((ybits[wi0]>>bit0)&1ull);
    int hd = (int)((hbits[wi0]>>bit0)&1ull);
    int sT = (int)((skel2[wi0]>>bit0)&1ull);
    int sH = (int)((skel2[NWORDS+wi0]>>bit0)&1ull);
    float dT = (float)acc[n];
    float dH = (float)acc[NTOT+n];
    float x0=P[v], x1=P[VOL+v];
    float p = 1.f/(1.f+expf(x0-x1));
    float sk = skelp[n];
    cl1 += (double)sk * yb;
    cl2 += (double)sk;
    cl3 += sT ? (double)p : 0.0;
    cl4 += (double)sT;
    float q_vl = yb ? fminf(dT, rmaxT_[b])/rmaxT_[b] : 0.f;
    float q_sl = 0.f;
    if(sT){ float t = (rmaxT_[b]-dT+rminT_[b])/rmaxT_[b]; q_sl = t*t; }
    float q_vp = fminf(dH, rmaxH_[b])/rmaxH_[b] * p;
    float q_sp = 0.f;
    if(sH & hd){ float t = (rmaxH_[b]-dH+rminH_[b])/rmaxH_[b]; q_sp = t*t*p; }
    i1  += (double)( q_sp * powf(q_sp+1e-4f, 0.7f) * q_vl );
    un1 += (double)( q_sp * (0.1f*q_sp + 0.9f*q_vl) );
    i2  += (double)( q_sl * powf(q_vp+1e-4f, 0.7f) * q_sl );
    un2 += (double)( q_sl * (0.1f*q_vp + 0.9f*q_sl) );
  }
  block_sum(sob,part,5,sd);
  block_sum(cl1,part,6,sd);  block_sum(cl2,part,7,sd);
  block_sum(cl3,part,8,sd);  block_sum(cl4,part,9,sd);
  block_sum(i1 ,part,10,sd); block_sum(un1,part,11,sd);
  block_sum(i2 ,part,12,sd); block_sum(un2,part,13,sd);
}

// ---------------- finalize scalar ----------------
__global__ __launch_bounds__(RT) void k_finalize(const double* __restrict__ part, float* __restrict__ out){
  __shared__ double sd[RT];
  __shared__ double tot[14];
  for(int s=0;s<14;s++){
    double v=0;
    for(int i=threadIdx.x;i<RB;i+=RT) v += part[(size_t)s*RB+i];
    sd[threadIdx.x]=v; __syncthreads();
    for(int k=RT>>1;k>0;k>>=1){ if((int)threadIdx.x<k) sd[threadIdx.x]+=sd[threadIdx.x+k]; __syncthreads(); }
    if(threadIdx.x==0) tot[s]=sd[0];
    __syncthreads();
  }
  if(threadIdx.x==0){
    const double N = (double)NTOT;
    double ce = tot[0]/N;
    double tp=tot[1], fp=tot[2]-tot[1], fn=tot[3]-tot[1];
    double dice = -((2.0*tp+1e-5)/(2.0*tp+fp+fn+1e-5));
    double conn = tot[4]/(2.0*N);
    double dir  = 1.0 - tot[5]/N;
    double tprec = (tot[6]+1.0)/(tot[7]+1.0);
    double tsens = (tot[8]+1.0)/(tot[9]+1.0);
    double cld = 1.0 - 2.0*tprec*tsens/(tprec+tsens);
    double u1 = 1.0 - (tot[10]+1.0)/(tot[11]+1.0);
    double u2 = 1.0 - (tot[12]+1.0)/(tot[13]+1.0);
    out[0] = (float)(dice+ce+cld+dir+conn+u1+u2);
  }
}

extern "C" void kernel_launch(void* const* d_in, const int* in_sizes, int n_in,
                              void* d_out, int out_size, void* d_ws, size_t ws_size,
                              hipStream_t stream)
{
  (void)in_sizes; (void)n_in; (void)out_size; (void)ws_size;
  const float* net = (const float*)d_in[0];
  const int*   tgt = (const int*)d_in[1];
  float* out = (float*)d_out;
  char* w = (char*)d_ws;
  const size_t MB = 1024*1024;
  float* F1 = (float*)(w + 0*MB);          // prob img (ping)
  float* F2 = (float*)(w + 8*MB);          // skel_pred (soft)
  float* F3 = (float*)(w + 16*MB);         // img pong
  u64* ybits = (u64*)(w + 24*MB);          // 256 KB
  u64* hbits = ybits + NWORDS;             // 256 KB
  u64* skel2 = hbits + NWORDS;             // 512 KB: [T][H]
  u64* bping = skel2 + 2*NWORDS;           // 512 KB: [T][H]
  u64* bpong = bping + 2*NWORDS;           // 512 KB
  u8*  dA    = (u8*)(bpong + 2*NWORDS);    // 4 MB
  u8*  dB    = dA + (size_t)2*NTOT;        // 4 MB
  double* part = (double*)(dB + (size_t)2*NTOT);
  u32* mm = (u32*)(part + (size_t)14*RB);

  init_mm<<<1, 64, 0, stream>>>(mm);
  k_init<<<RB, RT, 0, stream>>>(net, tgt, F1, ybits, hbits, bping, part);

  // float soft_skel(prob, 10): 11 fused dispatches
  fskel<true><<<512,256,0,stream>>>(F1, F3, F2);
  {
    float* pi=F1; float* po=F3;
    for(int i=0;i<10;i++){ fskel<false><<<512,256,0,stream>>>(pi,po,F2); float* t=pi; pi=po; po=t; }
  }
  // binary soft_skel for y_true and hard: 11 fused dispatches
  bskel<true><<<32,256,0,stream>>>(bping, bpong, skel2);
  {
    u64* pi=bping; u64* po=bpong;
    for(int i=0;i<10;i++){ bskel<false><<<32,256,0,stream>>>(pi,po,skel2); u64* t=pi; pi=po; po=t; }
  }
  // separable Chebyshev EDT (== 16-iter min-pool accumulation)
  const int GE = (2*NTOT)/256;
  edt_px<<<GE,256,0,stream>>>(ybits, hbits, dA);
  edt_pyz<128,128,7><<<GE,256,0,stream>>>(dA, dB);
  edt_pyz<16384,64,14><<<GE,256,0,stream>>>(dB, dA);

  rminmax<<<(2*NWORDS)/256,256,0,stream>>>(skel2, hbits, dA, mm);
  k_tail<<<RB,RT,0,stream>>>(net, F2, ybits, hbits, skel2, dA, mm, part);
  k_finalize<<<1,RT,0,stream>>>(part, out);
}